// Round 10
// baseline (291.478 us; speedup 1.0000x reference)
//
#include <hip/hip_runtime.h>
#include <cstdint>
#include <cstddef>

// Problem constants
constexpr int kHeads = 8;
constexpr int kDHead = 64;
constexpr int kC     = 512;   // channels
constexpr int kB     = 16;    // batch
constexpr int kN     = 1024;  // pixels per image (32*32)
constexpr int kHid   = 512;   // heads*dhead
constexpr int kKeys  = 1088;  // 64 (mem-kv zone, 4 real + 60 zero) + 1024
constexpr int kKVsz  = kKeys * kDHead;   // 69632 h16 per (b,h)

typedef _Float16 h16;
typedef _Float16 h8 __attribute__((ext_vector_type(8)));
typedef _Float16 h4 __attribute__((ext_vector_type(4)));
typedef _Float16 h2 __attribute__((ext_vector_type(2)));
typedef float f32x4 __attribute__((ext_vector_type(4)));

// ---------------------------------------------------------------------------
// Kernel 1: fused RMS-norm + transpose.
//   xh[b*1024+p][c] = x[b][c][p] * sqrt(512)/max(||x[:,p]||,1e-12)   (f16)
// ---------------------------------------------------------------------------
__global__ __launch_bounds__(256) void rms_transpose_kernel(
    const float* __restrict__ x, h16* __restrict__ xh)
{
  __shared__ float T[64 * 64];
  __shared__ float red[4][64];
  __shared__ float sl[64];
  const int t  = threadIdx.x;
  const int b  = blockIdx.x >> 4;
  const int p0 = (blockIdx.x & 15) << 6;
  const float* xb = x + (size_t)b * kC * kN + p0;

  const int pix = t & 63, sub = t >> 6;
  float sum = 0.f;
  #pragma unroll 8
  for (int c = sub * 128; c < sub * 128 + 128; ++c) {
    const float v = xb[(size_t)c * kN + pix];
    sum = fmaf(v, v, sum);
  }
  red[sub][pix] = sum;
  __syncthreads();
  if (t < 64) {
    const float tot = red[0][t] + red[1][t] + red[2][t] + red[3][t];
    sl[t] = 22.62741699796952f / fmaxf(sqrtf(tot), 1e-12f);
  }
  __syncthreads();

  for (int cc = 0; cc < 8; cc++) {
    const int c0 = cc * 64;
    #pragma unroll
    for (int i = 0; i < 4; i++) {
      const int r  = i * 16 + (t >> 4);
      const int pg = t & 15;
      const float4 v = *(const float4*)(xb + (size_t)(c0 + r) * kN + pg * 4);
      *(float4*)&T[r * 64 + ((pg ^ (r & 15)) << 2)] = v;
    }
    __syncthreads();
    #pragma unroll
    for (int i2 = 0; i2 < 2; i2++) {
      const int p  = i2 * 32 + (t >> 3);
      const int cg = t & 7;
      const float sc = sl[p];
      h16 hv[8];
      #pragma unroll
      for (int j = 0; j < 8; j++) {
        const int c = cg * 8 + j;
        const float v = T[c * 64 + (((p >> 2) ^ (c & 15)) << 2) + (p & 3)];
        hv[j] = (h16)(v * sc);
      }
      *(h8*)&xh[((size_t)b * kN + p0 + p) * kC + c0 + cg * 8] = *(h8*)hv;
    }
    __syncthreads();
  }
}

// ---------------------------------------------------------------------------
// Kernel 2: weight prep (f16).
//   wqh[o][c] = w_qkv[o][c]*(gamma[c]+1) * (o<512 ? 0.125*log2e : 1)
// ---------------------------------------------------------------------------
__global__ __launch_bounds__(64) void prep_w_kernel(
    const float* __restrict__ w_qkv, const float* __restrict__ gamma,
    const float* __restrict__ w_out, h16* __restrict__ wqh,
    h16* __restrict__ wouth)
{
  const int row = blockIdx.x;
  const int c0  = threadIdx.x * 8;
  if (row < 1536) {
    const float sc = (row < 512) ? 0.125f * 1.4426950408889634f : 1.f;
    const float4 a  = *(const float4*)(w_qkv + (size_t)row * kC + c0);
    const float4 b  = *(const float4*)(w_qkv + (size_t)row * kC + c0 + 4);
    const float4 g0 = *(const float4*)(gamma + c0);
    const float4 g1 = *(const float4*)(gamma + c0 + 4);
    h8 hv = { (h16)(a.x * (g0.x + 1.f) * sc), (h16)(a.y * (g0.y + 1.f) * sc),
              (h16)(a.z * (g0.z + 1.f) * sc), (h16)(a.w * (g0.w + 1.f) * sc),
              (h16)(b.x * (g1.x + 1.f) * sc), (h16)(b.y * (g1.y + 1.f) * sc),
              (h16)(b.z * (g1.z + 1.f) * sc), (h16)(b.w * (g1.w + 1.f) * sc) };
    *(h8*)&wqh[(size_t)row * kC + c0] = hv;
  } else {
    const int r = row - 1536;
    const float4 a = *(const float4*)(w_out + (size_t)r * kC + c0);
    const float4 b = *(const float4*)(w_out + (size_t)r * kC + c0 + 4);
    h8 hv = { (h16)a.x, (h16)a.y, (h16)a.z, (h16)a.w,
              (h16)b.x, (h16)b.y, (h16)b.z, (h16)b.w };
    *(h8*)&wouth[(size_t)r * kC + c0] = hv;
  }
}

// ---------------------------------------------------------------------------
// Kernel 2b: mem-kv zone fill. Keys 0..3 = mem_kv (per head, replicated per
// b), keys 4..63 = ZERO. Zero keys contribute exactly 2^-8 to l (subtracted
// in the attn epilogue) and 0 to O.
// ---------------------------------------------------------------------------
__global__ __launch_bounds__(64) void prep_memkv_kernel(
    const float* __restrict__ mem_kv, h16* __restrict__ Kh2,
    h16* __restrict__ VT2)
{
  const int bh = blockIdx.x;       // 0..127
  const int h  = bh & 7;
  const int t  = threadIdx.x;      // 0..63
  // K zone: row t (key t), 64 d
  h16* krow = Kh2 + (size_t)bh * kKVsz + t * kDHead;
  if (t < 4) {
    const float* src = mem_kv + (size_t)h * 256 + t * 64;
    #pragma unroll
    for (int j = 0; j < 64; j++) krow[j] = (h16)src[j];
  } else {
    #pragma unroll
    for (int j = 0; j < 8; j++) *(h8*)&krow[j * 8] = (h8)0;
  }
  // V zone: d = t, keys 0..63 of VT row
  h16* vrow = VT2 + (size_t)bh * kKVsz + (size_t)t * kKeys;
  h16 tmp[64];
  #pragma unroll
  for (int j = 0; j < 64; j++) tmp[j] = (h16)0.f;
  #pragma unroll
  for (int k = 0; k < 4; k++)
    tmp[k] = (h16)mem_kv[2048 + (size_t)h * 256 + k * 64 + t];
  #pragma unroll
  for (int j = 0; j < 8; j++) *(h8*)&vrow[j * 8] = *(h8*)&tmp[j * 8];
}

// ---------------------------------------------------------------------------
// Shared f16 MFMA GEMM mainloop: 128x128 tile, K=512, BK=64, double-buffered
// XOR-swizzled LDS, 4 waves (2x2), 64x64 per wave.
// ---------------------------------------------------------------------------
__device__ __forceinline__ void gemm_loop_f16(
    const h16* __restrict__ Ag, const h16* __restrict__ Bg,
    h16 (*__restrict__ As)[8192], h16 (*__restrict__ Bs)[8192],
    int t, int w, int g, int lo, f32x4 (&acc)[4][4])
{
  const int wo = (w >> 1) * 64, wp = (w & 1) * 64;
  h8 stA[4], stB[4];
  auto load = [&](int kt) {
    const int k0 = kt * 64;
    #pragma unroll
    for (int i = 0; i < 4; i++) {
      const int f = t + i * 256, r = f >> 3, cg = f & 7;
      stA[i] = *(const h8*)(Ag + (size_t)r * kC + k0 + cg * 8);
      stB[i] = *(const h8*)(Bg + (size_t)r * kC + k0 + cg * 8);
    }
  };
  auto store = [&](int buf) {
    #pragma unroll
    for (int i = 0; i < 4; i++) {
      const int f = t + i * 256, r = f >> 3, cg = f & 7;
      const int off = r * 64 + ((cg ^ (r & 7)) << 3);
      *(h8*)&As[buf][off] = stA[i];
      *(h8*)&Bs[buf][off] = stB[i];
    }
  };
  load(0); store(0); __syncthreads();
  int buf = 0;
  for (int kt = 0; kt < 8; kt++) {
    if (kt < 7) load(kt + 1);
    h8 bfr[4][2];
    #pragma unroll
    for (int ni = 0; ni < 4; ni++) {
      const int row = wp + ni * 16 + lo;
      #pragma unroll
      for (int kb = 0; kb < 2; kb++)
        bfr[ni][kb] = *(const h8*)&Bs[buf][row * 64 + (((kb * 4 + g) ^ (row & 7)) << 3)];
    }
    #pragma unroll
    for (int mi = 0; mi < 4; mi++) {
      const int row = wo + mi * 16 + lo;
      const h8 a0 = *(const h8*)&As[buf][row * 64 + (((    g) ^ (row & 7)) << 3)];
      const h8 a1 = *(const h8*)&As[buf][row * 64 + (((4 + g) ^ (row & 7)) << 3)];
      #pragma unroll
      for (int ni = 0; ni < 4; ni++) {
        acc[mi][ni] = __builtin_amdgcn_mfma_f32_16x16x32_f16(a0, bfr[ni][0], acc[mi][ni], 0, 0, 0);
        acc[mi][ni] = __builtin_amdgcn_mfma_f32_16x16x32_f16(a1, bfr[ni][1], acc[mi][ni], 0, 0, 0);
      }
    }
    if (kt < 7) store(buf ^ 1);
    __syncthreads();
    buf ^= 1;
  }
}

// ---------------------------------------------------------------------------
// Kernel 3: QKV projection, f16 MFMA. K/V written into the padded buffers
// at key offset 64 (keys 0..63 are the mem-kv zone).
// ---------------------------------------------------------------------------
__global__ __launch_bounds__(256) void qkv_mfma_kernel(
    const h16* __restrict__ xh, const h16* __restrict__ wqh,
    h16* __restrict__ Qh, h16* __restrict__ Kh2, h16* __restrict__ VT2)
{
  __shared__ h16 As[2][8192];
  __shared__ h16 Bs[2][8192];
  const int t = threadIdx.x, lane = t & 63, w = t >> 6, g = lane >> 4, lo = lane & 15;
  const int o0 = blockIdx.x * 128;
  const int p0 = blockIdx.y * 128;
  const int b  = blockIdx.z;
  const h16* Ag = wqh + (size_t)o0 * kC;
  const h16* Bg = xh + ((size_t)b * kN + p0) * kC;

  f32x4 acc[4][4];
  #pragma unroll
  for (int mi = 0; mi < 4; mi++)
    #pragma unroll
    for (int ni = 0; ni < 4; ni++) { f32x4 z = {0.f, 0.f, 0.f, 0.f}; acc[mi][ni] = z; }

  gemm_loop_f16(Ag, Bg, As, Bs, t, w, g, lo, acc);

  const int o_wave = o0 + (w >> 1) * 64;     // block-uniform section
  const int which  = o_wave >> 9;
  const int head   = (o_wave >> 6) & 7;
  const size_t bh  = (size_t)b * kHeads + head;
  const int pglob  = p0 + (w & 1) * 64;

  if (which == 2) {
    h16* Vdst = VT2 + bh * kKVsz;
    #pragma unroll
    for (int mi = 0; mi < 4; mi++)
      #pragma unroll
      for (int ni = 0; ni < 4; ni++) {
        const int p = pglob + ni * 16 + lo;
        #pragma unroll
        for (int r = 0; r < 4; r++) {
          const int d = mi * 16 + g * 4 + r;
          Vdst[(size_t)d * kKeys + 64 + p] = (h16)((const float*)&acc[mi][ni])[r];
        }
      }
  } else {
    h16* lw = &As[0][0] + w * 4096;          // per-wave 64x64 [p][d] swizzled
    #pragma unroll
    for (int mi = 0; mi < 4; mi++) {
      const int gran0 = mi * 2 + (g >> 1);
      const int off   = (g & 1) * 4;
      #pragma unroll
      for (int ni = 0; ni < 4; ni++) {
        const int p = ni * 16 + lo;
        h4 pv = { (h16)acc[mi][ni].x, (h16)acc[mi][ni].y,
                  (h16)acc[mi][ni].z, (h16)acc[mi][ni].w };
        *(h4*)&lw[p * 64 + ((gran0 ^ (p & 7)) << 3) + off] = pv;
      }
    }
    __syncthreads();
    h16* dst = which ? (Kh2 + bh * kKVsz + 64 * kDHead) : (Qh + bh * (size_t)(kN * kDHead));
    #pragma unroll
    for (int i = 0; i < 8; i++) {
      const int p  = i * 8 + (lane >> 3);
      const int dg = lane & 7;
      const h8 v = *(const h8*)&lw[p * 64 + ((dg ^ (p & 7)) << 3)];
      *(h8*)&dst[((size_t)pglob + p) * kDHead + dg * 8] = v;
    }
  }
}

// ---------------------------------------------------------------------------
// Kernel 4: flash attention — barrier-free, LDS-free, one wave per 32-query
// job. Fixed-max softmax (P = exp2(s-8), -8 in the MFMA C-init); K and V^T
// fragments loaded directly from global (L2-hot; per-lane contiguous 16B/8B).
// Mem-kv is a pre-padded uniform first tile; zero-keys' exact l contribution
// (60 * 2^-8) is subtracted in the epilogue.
// ---------------------------------------------------------------------------
__global__ __launch_bounds__(64, 3) void attn_mfma_kernel(
    const h16* __restrict__ Qh, const h16* __restrict__ Kh2,
    const h16* __restrict__ VT2, h16* __restrict__ ah)
{
  const int lane = threadIdx.x;
  const int g  = lane >> 4;
  const int lo = lane & 15;
  // XCD swizzle: all 32 q-jobs of one (b,h) land on one XCD.
  const int id   = blockIdx.x;          // 0..4095
  const int xcd  = id & 7;
  const int slot = id >> 3;             // 0..511
  const int grp  = xcd * 16 + (slot & 15);   // (b,h) 0..127
  const int qt   = slot >> 4;           // 0..31
  const int h = grp & 7, b = grp >> 3;
  const int q0 = qt * 32;

  const h16* Qg = Qh  + (size_t)grp * (kN * kDHead);
  const h16* Kg = Kh2 + (size_t)grp * kKVsz;
  const h16* Vg = VT2 + (size_t)grp * kKVsz;

  h8 qf[2][2];
  #pragma unroll
  for (int ni = 0; ni < 2; ni++)
    #pragma unroll
    for (int kb = 0; kb < 2; kb++)
      qf[ni][kb] = *(const h8*)(Qg + (size_t)(q0 + ni*16 + lo) * 64 + kb*32 + g*8);

  f32x4 o[2][4];   // [q-block][d-block]: q = qb*16+g*4+reg, d = db*16+lo
  #pragma unroll
  for (int qb = 0; qb < 2; qb++)
    #pragma unroll
    for (int db = 0; db < 4; db++) { f32x4 z = {0.f,0.f,0.f,0.f}; o[qb][db] = z; }
  float lst[2] = {0.f, 0.f};
  const f32x4 cinit = {-8.f, -8.f, -8.f, -8.f};

  for (int kt = 0; kt < 17; kt++) {
    const h16* Kt = Kg + kt * (64 * kDHead);   // [64 keys][64 d]
    const int key0 = kt * 64;

    // QK^T (swapped): S^T[key][q] - 8; key = mi*16+g*4+reg, q = ni*16+lo
    f32x4 s[4][2];
    __builtin_amdgcn_s_setprio(1);
    #pragma unroll
    for (int mi = 0; mi < 4; mi++) {
      const int row = mi*16 + lo;
      const h8 k0 = *(const h8*)(Kt + row*64      + g*8);
      const h8 k1 = *(const h8*)(Kt + row*64 + 32 + g*8);
      #pragma unroll
      for (int ni = 0; ni < 2; ni++) {
        f32x4 acc = __builtin_amdgcn_mfma_f32_16x16x32_f16(k0, qf[ni][0], cinit, 0, 0, 0);
        acc = __builtin_amdgcn_mfma_f32_16x16x32_f16(k1, qf[ni][1], acc, 0, 0, 0);
        s[mi][ni] = acc;
      }
    }
    __builtin_amdgcn_s_setprio(0);

    // P = exp2(s); accumulate per-lane l; pack to f16 PV A-fragments
    h4 p4[4][2];
    #pragma unroll
    for (int ni = 0; ni < 2; ni++) {
      #pragma unroll
      for (int mi = 0; mi < 4; mi++) {
        const float px = exp2f(s[mi][ni].x);
        const float py = exp2f(s[mi][ni].y);
        const float pz = exp2f(s[mi][ni].z);
        const float pw = exp2f(s[mi][ni].w);
        lst[ni] += (px + py) + (pz + pw);
        const h2 a = __builtin_bit_cast(h2, __builtin_amdgcn_cvt_pkrtz(px, py));
        const h2 c = __builtin_bit_cast(h2, __builtin_amdgcn_cvt_pkrtz(pz, pw));
        p4[mi][ni] = __builtin_shufflevector(a, c, 0, 1, 2, 3);
      }
    }

    // PV via 16x16x16: B-frag = V[key=mi*16+g*4..+3][d=db*16+lo], direct
    // from global VT (8B contiguous per lane).
    __builtin_amdgcn_s_setprio(1);
    #pragma unroll
    for (int db = 0; db < 4; db++) {
      const int d = db*16 + lo;
      h4 v4[4];
      #pragma unroll
      for (int mi = 0; mi < 4; mi++)
        v4[mi] = *(const h4*)(Vg + (size_t)d * kKeys + key0 + mi*16 + g*4);
      #pragma unroll
      for (int qb = 0; qb < 2; qb++)
        #pragma unroll
        for (int mi = 0; mi < 4; mi++)
          o[qb][db] = __builtin_amdgcn_mfma_f32_16x16x16f16(p4[mi][qb], v4[mi], o[qb][db], 0, 0, 0);
    }
    __builtin_amdgcn_s_setprio(0);
  }

  // epilogue: reduce l across lane-groups, remove zero-key contribution
  #pragma unroll
  for (int qb = 0; qb < 2; qb++) {
    float l = lst[qb];
    l += __shfl_xor(l, 16);
    l += __shfl_xor(l, 32);
    l -= 0.234375f;                 // 60 zero-keys * 2^-8, exact
    const float il = 1.f / l;
    const float i0 = __shfl(il, g*4 + 0);
    const float i1 = __shfl(il, g*4 + 1);
    const float i2 = __shfl(il, g*4 + 2);
    const float i3 = __shfl(il, g*4 + 3);
    const int qg = (b << 10) + q0 + qb*16 + g*4;
    #pragma unroll
    for (int db = 0; db < 4; db++) {
      const int c = h*64 + db*16 + lo;
      ah[(size_t)(qg + 0) * kHid + c] = (h16)(o[qb][db].x * i0);
      ah[(size_t)(qg + 1) * kHid + c] = (h16)(o[qb][db].y * i1);
      ah[(size_t)(qg + 2) * kHid + c] = (h16)(o[qb][db].z * i2);
      ah[(size_t)(qg + 3) * kHid + c] = (h16)(o[qb][db].w * i3);
    }
  }
}

// ---------------------------------------------------------------------------
// Kernel 5: output projection, f16 MFMA. C[o][p] -> out[b][o][p] fp32.
// ---------------------------------------------------------------------------
__global__ __launch_bounds__(256) void out_mfma_kernel(
    const h16* __restrict__ ah, const h16* __restrict__ wouth,
    float* __restrict__ out)
{
  __shared__ h16 As[2][8192];
  __shared__ h16 Bs[2][8192];
  const int t = threadIdx.x, lane = t & 63, w = t >> 6, g = lane >> 4, lo = lane & 15;
  const int o0 = blockIdx.x * 128;
  const int p0 = blockIdx.y * 128;
  const int b  = blockIdx.z;
  const h16* Ag = wouth + (size_t)o0 * kC;
  const h16* Bg = ah + ((size_t)b * kN + p0) * kC;

  f32x4 acc[4][4];
  #pragma unroll
  for (int mi = 0; mi < 4; mi++)
    #pragma unroll
    for (int ni = 0; ni < 4; ni++) { f32x4 z = {0.f, 0.f, 0.f, 0.f}; acc[mi][ni] = z; }

  gemm_loop_f16(Ag, Bg, As, Bs, t, w, g, lo, acc);

  const int ow = o0 + (w >> 1) * 64;
  const int pw = p0 + (w & 1) * 64;
  #pragma unroll
  for (int mi = 0; mi < 4; mi++)
    #pragma unroll
    for (int ni = 0; ni < 4; ni++) {
      const int p = pw + ni * 16 + lo;
      #pragma unroll
      for (int r = 0; r < 4; r++) {
        const int oc = ow + mi * 16 + g * 4 + r;
        out[((size_t)b * kHid + oc) * kN + p] = ((const float*)&acc[mi][ni])[r];
      }
    }
}

// ---------------------------------------------------------------------------
// Launch
// ---------------------------------------------------------------------------
extern "C" void kernel_launch(void* const* d_in, const int* in_sizes, int n_in,
                              void* d_out, int out_size, void* d_ws, size_t ws_size,
                              hipStream_t stream) {
  (void)in_sizes; (void)n_in; (void)out_size; (void)ws_size;
  const float* x      = (const float*)d_in[0];
  const float* gamma  = (const float*)d_in[1];
  const float* mem_kv = (const float*)d_in[2];
  const float* w_qkv  = (const float*)d_in[3];
  const float* w_out  = (const float*)d_in[4];
  float* out = (float*)d_out;

  // ws layout (h16 units), total 52,428,800 h16 = 100 MiB
  h16* xh    = (h16*)d_ws;                       // 16,777,216
  h16* Qh    = xh   + (size_t)16777216;          //  8,388,608
  h16* Kh2   = Qh   + (size_t)8388608;           //  8,912,896 (128 x 1088 x 64)
  h16* VT2   = Kh2  + (size_t)8912896;           //  8,912,896 (128 x 64 x 1088)
  h16* ah    = VT2  + (size_t)8912896;           //  8,388,608
  h16* wqh   = ah   + (size_t)8388608;           //    786,432
  h16* wouth = wqh  + (size_t)786432;            //    262,144

  rms_transpose_kernel<<<256, 256, 0, stream>>>(x, xh);
  prep_w_kernel<<<2048, 64, 0, stream>>>(w_qkv, gamma, w_out, wqh, wouth);
  prep_memkv_kernel<<<128, 64, 0, stream>>>(mem_kv, Kh2, VT2);
  qkv_mfma_kernel<<<dim3(12, 8, 16), 256, 0, stream>>>(xh, wqh, Qh, Kh2, VT2);
  attn_mfma_kernel<<<4096, 64, 0, stream>>>(Qh, Kh2, VT2, ah);
  out_mfma_kernel<<<dim3(4, 8, 16), 256, 0, stream>>>(ah, wouth, out);
}

// Round 11
// 150.878 us; speedup vs baseline: 1.9319x; 1.9319x over previous
//
#include <hip/hip_runtime.h>
#include <cstdint>
#include <cstddef>

// Problem constants
constexpr int kHeads = 8;
constexpr int kDHead = 64;
constexpr int kC     = 512;   // channels
constexpr int kB     = 16;    // batch
constexpr int kN     = 1024;  // pixels per image (32*32)
constexpr int kHid   = 512;   // heads*dhead

typedef _Float16 h16;
typedef _Float16 h8 __attribute__((ext_vector_type(8)));
typedef _Float16 h4 __attribute__((ext_vector_type(4)));
typedef _Float16 h2 __attribute__((ext_vector_type(2)));
typedef float f32x4 __attribute__((ext_vector_type(4)));

// ---------------------------------------------------------------------------
// Kernel 1: fused RMS-norm + transpose.
//   xh[b*1024+p][c] = x[b][c][p] * sqrt(512)/max(||x[:,p]||,1e-12)   (f16)
// ---------------------------------------------------------------------------
__global__ __launch_bounds__(256) void rms_transpose_kernel(
    const float* __restrict__ x, h16* __restrict__ xh)
{
  __shared__ float T[64 * 64];
  __shared__ float red[4][64];
  __shared__ float sl[64];
  const int t  = threadIdx.x;
  const int b  = blockIdx.x >> 4;
  const int p0 = (blockIdx.x & 15) << 6;
  const float* xb = x + (size_t)b * kC * kN + p0;

  const int pix = t & 63, sub = t >> 6;
  float sum = 0.f;
  #pragma unroll 8
  for (int c = sub * 128; c < sub * 128 + 128; ++c) {
    const float v = xb[(size_t)c * kN + pix];
    sum = fmaf(v, v, sum);
  }
  red[sub][pix] = sum;
  __syncthreads();
  if (t < 64) {
    const float tot = red[0][t] + red[1][t] + red[2][t] + red[3][t];
    sl[t] = 22.62741699796952f / fmaxf(sqrtf(tot), 1e-12f);
  }
  __syncthreads();

  for (int cc = 0; cc < 8; cc++) {
    const int c0 = cc * 64;
    #pragma unroll
    for (int i = 0; i < 4; i++) {
      const int r  = i * 16 + (t >> 4);
      const int pg = t & 15;
      const float4 v = *(const float4*)(xb + (size_t)(c0 + r) * kN + pg * 4);
      *(float4*)&T[r * 64 + ((pg ^ (r & 15)) << 2)] = v;
    }
    __syncthreads();
    #pragma unroll
    for (int i2 = 0; i2 < 2; i2++) {
      const int p  = i2 * 32 + (t >> 3);
      const int cg = t & 7;
      const float sc = sl[p];
      h16 hv[8];
      #pragma unroll
      for (int j = 0; j < 8; j++) {
        const int c = cg * 8 + j;
        const float v = T[c * 64 + (((p >> 2) ^ (c & 15)) << 2) + (p & 3)];
        hv[j] = (h16)(v * sc);
      }
      *(h8*)&xh[((size_t)b * kN + p0 + p) * kC + c0 + cg * 8] = *(h8*)hv;
    }
    __syncthreads();
  }
}

// ---------------------------------------------------------------------------
// Kernel 2: weight prep (f16).
//   wqh[o][c] = w_qkv[o][c]*(gamma[c]+1) * (o<512 ? 0.125*log2e : 1)
// ---------------------------------------------------------------------------
__global__ __launch_bounds__(64) void prep_w_kernel(
    const float* __restrict__ w_qkv, const float* __restrict__ gamma,
    const float* __restrict__ w_out, h16* __restrict__ wqh,
    h16* __restrict__ wouth)
{
  const int row = blockIdx.x;
  const int c0  = threadIdx.x * 8;
  if (row < 1536) {
    const float sc = (row < 512) ? 0.125f * 1.4426950408889634f : 1.f;
    const float4 a  = *(const float4*)(w_qkv + (size_t)row * kC + c0);
    const float4 b  = *(const float4*)(w_qkv + (size_t)row * kC + c0 + 4);
    const float4 g0 = *(const float4*)(gamma + c0);
    const float4 g1 = *(const float4*)(gamma + c0 + 4);
    h8 hv = { (h16)(a.x * (g0.x + 1.f) * sc), (h16)(a.y * (g0.y + 1.f) * sc),
              (h16)(a.z * (g0.z + 1.f) * sc), (h16)(a.w * (g0.w + 1.f) * sc),
              (h16)(b.x * (g1.x + 1.f) * sc), (h16)(b.y * (g1.y + 1.f) * sc),
              (h16)(b.z * (g1.z + 1.f) * sc), (h16)(b.w * (g1.w + 1.f) * sc) };
    *(h8*)&wqh[(size_t)row * kC + c0] = hv;
  } else {
    const int r = row - 1536;
    const float4 a = *(const float4*)(w_out + (size_t)r * kC + c0);
    const float4 b = *(const float4*)(w_out + (size_t)r * kC + c0 + 4);
    h8 hv = { (h16)a.x, (h16)a.y, (h16)a.z, (h16)a.w,
              (h16)b.x, (h16)b.y, (h16)b.z, (h16)b.w };
    *(h8*)&wouth[(size_t)r * kC + c0] = hv;
  }
}

// ---------------------------------------------------------------------------
// Shared f16 MFMA GEMM mainloop: 128x128 tile, K=512, BK=64, double-buffered
// XOR-swizzled LDS, 4 waves (2x2), 64x64 per wave.
// ---------------------------------------------------------------------------
__device__ __forceinline__ void gemm_loop_f16(
    const h16* __restrict__ Ag, const h16* __restrict__ Bg,
    h16 (*__restrict__ As)[8192], h16 (*__restrict__ Bs)[8192],
    int t, int w, int g, int lo, f32x4 (&acc)[4][4])
{
  const int wo = (w >> 1) * 64, wp = (w & 1) * 64;
  h8 stA[4], stB[4];
  auto load = [&](int kt) {
    const int k0 = kt * 64;
    #pragma unroll
    for (int i = 0; i < 4; i++) {
      const int f = t + i * 256, r = f >> 3, cg = f & 7;
      stA[i] = *(const h8*)(Ag + (size_t)r * kC + k0 + cg * 8);
      stB[i] = *(const h8*)(Bg + (size_t)r * kC + k0 + cg * 8);
    }
  };
  auto store = [&](int buf) {
    #pragma unroll
    for (int i = 0; i < 4; i++) {
      const int f = t + i * 256, r = f >> 3, cg = f & 7;
      const int off = r * 64 + ((cg ^ (r & 7)) << 3);
      *(h8*)&As[buf][off] = stA[i];
      *(h8*)&Bs[buf][off] = stB[i];
    }
  };
  load(0); store(0); __syncthreads();
  int buf = 0;
  for (int kt = 0; kt < 8; kt++) {
    if (kt < 7) load(kt + 1);
    h8 bfr[4][2];
    #pragma unroll
    for (int ni = 0; ni < 4; ni++) {
      const int row = wp + ni * 16 + lo;
      #pragma unroll
      for (int kb = 0; kb < 2; kb++)
        bfr[ni][kb] = *(const h8*)&Bs[buf][row * 64 + (((kb * 4 + g) ^ (row & 7)) << 3)];
    }
    #pragma unroll
    for (int mi = 0; mi < 4; mi++) {
      const int row = wo + mi * 16 + lo;
      const h8 a0 = *(const h8*)&As[buf][row * 64 + (((    g) ^ (row & 7)) << 3)];
      const h8 a1 = *(const h8*)&As[buf][row * 64 + (((4 + g) ^ (row & 7)) << 3)];
      #pragma unroll
      for (int ni = 0; ni < 4; ni++) {
        acc[mi][ni] = __builtin_amdgcn_mfma_f32_16x16x32_f16(a0, bfr[ni][0], acc[mi][ni], 0, 0, 0);
        acc[mi][ni] = __builtin_amdgcn_mfma_f32_16x16x32_f16(a1, bfr[ni][1], acc[mi][ni], 0, 0, 0);
      }
    }
    if (kt < 7) store(buf ^ 1);
    __syncthreads();
    buf ^= 1;
  }
}

// ---------------------------------------------------------------------------
// Kernel 3: QKV projection, f16 MFMA.
// ---------------------------------------------------------------------------
__global__ __launch_bounds__(256) void qkv_mfma_kernel(
    const h16* __restrict__ xh, const h16* __restrict__ wqh,
    h16* __restrict__ Qh, h16* __restrict__ Kh, h16* __restrict__ VTh)
{
  __shared__ h16 As[2][8192];
  __shared__ h16 Bs[2][8192];
  const int t = threadIdx.x, lane = t & 63, w = t >> 6, g = lane >> 4, lo = lane & 15;
  const int o0 = blockIdx.x * 128;
  const int p0 = blockIdx.y * 128;
  const int b  = blockIdx.z;
  const h16* Ag = wqh + (size_t)o0 * kC;
  const h16* Bg = xh + ((size_t)b * kN + p0) * kC;

  f32x4 acc[4][4];
  #pragma unroll
  for (int mi = 0; mi < 4; mi++)
    #pragma unroll
    for (int ni = 0; ni < 4; ni++) { f32x4 z = {0.f, 0.f, 0.f, 0.f}; acc[mi][ni] = z; }

  gemm_loop_f16(Ag, Bg, As, Bs, t, w, g, lo, acc);

  const int o_wave = o0 + (w >> 1) * 64;     // block-uniform section
  const int which  = o_wave >> 9;
  const int head   = (o_wave >> 6) & 7;
  const size_t bh  = (size_t)b * kHeads + head;
  const int pglob  = p0 + (w & 1) * 64;

  if (which == 2) {
    h16* Vdst = VTh + bh * (size_t)(kN * kDHead);
    #pragma unroll
    for (int mi = 0; mi < 4; mi++)
      #pragma unroll
      for (int ni = 0; ni < 4; ni++) {
        const int p = pglob + ni * 16 + lo;
        #pragma unroll
        for (int r = 0; r < 4; r++) {
          const int d = mi * 16 + g * 4 + r;
          Vdst[(size_t)d * kN + p] = (h16)((const float*)&acc[mi][ni])[r];
        }
      }
  } else {
    h16* lw = &As[0][0] + w * 4096;          // per-wave 64x64 [p][d] swizzled
    #pragma unroll
    for (int mi = 0; mi < 4; mi++) {
      const int gran0 = mi * 2 + (g >> 1);
      const int off   = (g & 1) * 4;
      #pragma unroll
      for (int ni = 0; ni < 4; ni++) {
        const int p = ni * 16 + lo;
        h4 pv = { (h16)acc[mi][ni].x, (h16)acc[mi][ni].y,
                  (h16)acc[mi][ni].z, (h16)acc[mi][ni].w };
        *(h4*)&lw[p * 64 + ((gran0 ^ (p & 7)) << 3) + off] = pv;
      }
    }
    __syncthreads();
    h16* dst = (which ? Kh : Qh) + bh * (size_t)(kN * kDHead);
    #pragma unroll
    for (int i = 0; i < 8; i++) {
      const int p  = i * 8 + (lane >> 3);
      const int dg = lane & 7;
      const h8 v = *(const h8*)&lw[p * 64 + ((dg ^ (p & 7)) << 3)];
      *(h8*)&dst[((size_t)pglob + p) * kDHead + dg * 8] = v;
    }
  }
}

// ---------------------------------------------------------------------------
// Kernel 4: flash attention. LDS-staged double buffer (R7 loop style, no
// lambda -> no spill). Fixed-max softmax: P = exp2(s-8), -8 folded into the
// MFMA C-init; mem-kv tile zero-padded (keys 4..63 = 0) so NO masking -- the
// 60 zero-keys contribute exactly 60*2^-8 to l, subtracted in the epilogue.
// PV runs at FULL MFMA rate via permuted-key 16x16x32: the MFMA k-index
// g*8+j maps to key (j>>2)*16+g*4+(j&3), so A = concat(p4[2c],p4[2c+1]) and
// B = concat(v4[2c],v4[2c+1]) -- zero extra data movement, half the PV
// instructions vs 16x16x16.
// ---------------------------------------------------------------------------
__global__ __launch_bounds__(256, 3) void attn_mfma_kernel(
    const h16* __restrict__ Qh, const h16* __restrict__ Kh,
    const h16* __restrict__ VTh, const float* __restrict__ mem_kv,
    h16* __restrict__ ah)
{
  __shared__ h16 Kl[2][4096];   // [key][d], granule-XOR-swizzled by key&7
  __shared__ h16 Vl[2][4096];   // [d][key], granule-XOR-swizzled by d&7

  const int t    = threadIdx.x;
  const int lane = t & 63;
  const int w    = t >> 6;
  const int g    = lane >> 4;
  const int lo   = lane & 15;
  // XCD grouping: the 8 qt-blocks of one (b,h) land on one XCD (id%8 fixed).
  const int id   = blockIdx.x;
  const int xcd  = id & 7;
  const int slot = id >> 3;                  // 0..127 within XCD
  const int grp  = xcd * 16 + (slot & 15);   // (b,h) group 0..127
  const int qt   = slot >> 4;                // 0..7
  const int h = grp & 7, b = grp >> 3;

  const h16* Qg = Qh  + (size_t)grp * 65536;
  const h16* Kg = Kh  + (size_t)grp * 65536;
  const h16* Vg = VTh + (size_t)grp * 65536;
  const int q0 = qt * 128 + w * 32;

  h8 qf[2][2];
  #pragma unroll
  for (int ni = 0; ni < 2; ni++)
    #pragma unroll
    for (int kb = 0; kb < 2; kb++)
      qf[ni][kb] = *(const h8*)(Qg + (size_t)(q0 + ni*16 + lo) * 64 + kb*32 + g*8);

  // stage mem-kv tile into buffer 0 (keys 4..63 zero-filled; no masking later)
  {
    const int kr = t >> 2, dq = (t & 3) << 4;
    h16 hv[16];
    if (kr < 4) {
      const float* src = mem_kv + (size_t)h * 256 + kr * 64 + dq;
      #pragma unroll
      for (int i = 0; i < 16; i++) hv[i] = (h16)src[i];
    } else {
      #pragma unroll
      for (int i = 0; i < 16; i++) hv[i] = (h16)0.f;
    }
    const int sw = (kr & 7) << 3;
    *(h8*)&Kl[0][kr*64 + ( dq      ^ sw)] = *(h8*)&hv[0];
    *(h8*)&Kl[0][kr*64 + ((dq + 8) ^ sw)] = *(h8*)&hv[8];

    const int d = t >> 2, kq = (t & 3) << 4;
    h16 vv[16];
    #pragma unroll
    for (int i = 0; i < 16; i++) vv[i] = (h16)0.f;
    if (kq == 0) {
      const float* src = mem_kv + 2048 + (size_t)h * 256 + d;
      #pragma unroll
      for (int i = 0; i < 4; i++) vv[i] = (h16)src[i * 64];
    }
    const int sv = (d & 7) << 3;
    *(h8*)&Vl[0][d*64 + ( kq      ^ sv)] = *(h8*)&vv[0];
    *(h8*)&Vl[0][d*64 + ((kq + 8) ^ sv)] = *(h8*)&vv[8];
  }
  __syncthreads();

  f32x4 o[2][4];   // [q-block][d-block]: q = qb*16+g*4+reg, d = db*16+lo
  #pragma unroll
  for (int qb = 0; qb < 2; qb++)
    #pragma unroll
    for (int db = 0; db < 4; db++) { f32x4 z = {0.f,0.f,0.f,0.f}; o[qb][db] = z; }
  float lst[2] = {0.f, 0.f};   // per-lane partial l (reduced in epilogue)
  const f32x4 cinit = {-8.f, -8.f, -8.f, -8.f};

  h8 stK[2], stV[2];
  #pragma unroll 1
  for (int kt = 0; kt <= 16; kt++) {
    if (kt < 16) {   // issue next-tile global loads (hidden under compute)
      const size_t key0 = (size_t)kt * 64;
      #pragma unroll
      for (int ps = 0; ps < 2; ps++) {
        const int f = t + ps*256, r = f >> 3, cb = (f & 7) << 3;
        stK[ps] = *(const h8*)(Kg + (key0 + r) * 64 + cb);
        stV[ps] = *(const h8*)(Vg + (size_t)r * 1024 + key0 + cb);
      }
    }
    const h16* KL = Kl[kt & 1];
    const h16* VL = Vl[kt & 1];

    // ---- QK^T (swapped): S^T[key][q] - 8; key = mi*16+g*4+reg, q = ni*16+lo
    f32x4 s[4][2];
    __builtin_amdgcn_s_setprio(1);
    #pragma unroll
    for (int mi = 0; mi < 4; mi++) {
      const int row = mi*16 + lo;
      const int sw = (row & 7) << 3;
      const h8 k0 = *(const h8*)&KL[row*64 + (( g*8)      ^ sw)];
      const h8 k1 = *(const h8*)&KL[row*64 + ((32 + g*8)  ^ sw)];
      #pragma unroll
      for (int ni = 0; ni < 2; ni++) {
        f32x4 acc = __builtin_amdgcn_mfma_f32_16x16x32_f16(k0, qf[ni][0], cinit, 0, 0, 0);
        acc = __builtin_amdgcn_mfma_f32_16x16x32_f16(k1, qf[ni][1], acc, 0, 0, 0);
        s[mi][ni] = acc;
      }
    }
    __builtin_amdgcn_s_setprio(0);

    // ---- P = exp2(s); accumulate per-lane l; pack to f16 fragments ----
    h4 p4[4][2];
    #pragma unroll
    for (int ni = 0; ni < 2; ni++) {
      #pragma unroll
      for (int mi = 0; mi < 4; mi++) {
        const float px = exp2f(s[mi][ni].x);
        const float py = exp2f(s[mi][ni].y);
        const float pz = exp2f(s[mi][ni].z);
        const float pw = exp2f(s[mi][ni].w);
        lst[ni] += (px + py) + (pz + pw);
        const h2 a = __builtin_bit_cast(h2, __builtin_amdgcn_cvt_pkrtz(px, py));
        const h2 c = __builtin_bit_cast(h2, __builtin_amdgcn_cvt_pkrtz(pz, pw));
        p4[mi][ni] = __builtin_shufflevector(a, c, 0, 1, 2, 3);
      }
    }

    // ---- PV via permuted-key 16x16x32 (full rate) ----
    __builtin_amdgcn_s_setprio(1);
    #pragma unroll
    for (int db = 0; db < 4; db++) {
      const int d = db*16 + lo;
      const int sw = (d & 7) << 3;
      h4 v4[4];
      #pragma unroll
      for (int mi = 0; mi < 4; mi++)
        v4[mi] = *(const h4*)&VL[d*64 + ((mi*16 + (g>>1)*8) ^ sw) + (g&1)*4];
      const h8 vB0 = __builtin_shufflevector(v4[0], v4[1], 0, 1, 2, 3, 4, 5, 6, 7);
      const h8 vB1 = __builtin_shufflevector(v4[2], v4[3], 0, 1, 2, 3, 4, 5, 6, 7);
      #pragma unroll
      for (int qb = 0; qb < 2; qb++) {
        const h8 pA0 = __builtin_shufflevector(p4[0][qb], p4[1][qb], 0, 1, 2, 3, 4, 5, 6, 7);
        const h8 pA1 = __builtin_shufflevector(p4[2][qb], p4[3][qb], 0, 1, 2, 3, 4, 5, 6, 7);
        o[qb][db] = __builtin_amdgcn_mfma_f32_16x16x32_f16(pA0, vB0, o[qb][db], 0, 0, 0);
        o[qb][db] = __builtin_amdgcn_mfma_f32_16x16x32_f16(pA1, vB1, o[qb][db], 0, 0, 0);
      }
    }
    __builtin_amdgcn_s_setprio(0);

    // ---- write staged next tile into the other buffer ----
    if (kt < 16) {
      #pragma unroll
      for (int ps = 0; ps < 2; ps++) {
        const int f = t + ps*256, r = f >> 3, cb = (f & 7) << 3;
        const int sw = (r & 7) << 3;
        *(h8*)&Kl[(kt + 1) & 1][r*64 + (cb ^ sw)] = stK[ps];
        *(h8*)&Vl[(kt + 1) & 1][r*64 + (cb ^ sw)] = stV[ps];
      }
    }
    __syncthreads();
  }

  // ---- epilogue: reduce l, remove zero-key contribution, write ah ----
  #pragma unroll
  for (int qb = 0; qb < 2; qb++) {
    float l = lst[qb];
    l += __shfl_xor(l, 16);
    l += __shfl_xor(l, 32);
    l -= 0.234375f;                 // 60 zero-keys * 2^-8, exact
    const float il = 1.f / l;
    const float i0 = __shfl(il, g*4 + 0);
    const float i1 = __shfl(il, g*4 + 1);
    const float i2 = __shfl(il, g*4 + 2);
    const float i3 = __shfl(il, g*4 + 3);
    const int qg = (b << 10) + q0 + qb*16 + g*4;
    #pragma unroll
    for (int db = 0; db < 4; db++) {
      const int c = h*64 + db*16 + lo;
      ah[(size_t)(qg + 0) * kHid + c] = (h16)(o[qb][db].x * i0);
      ah[(size_t)(qg + 1) * kHid + c] = (h16)(o[qb][db].y * i1);
      ah[(size_t)(qg + 2) * kHid + c] = (h16)(o[qb][db].z * i2);
      ah[(size_t)(qg + 3) * kHid + c] = (h16)(o[qb][db].w * i3);
    }
  }
}

// ---------------------------------------------------------------------------
// Kernel 5: output projection, f16 MFMA. C[o][p] -> out[b][o][p] fp32.
// ---------------------------------------------------------------------------
__global__ __launch_bounds__(256) void out_mfma_kernel(
    const h16* __restrict__ ah, const h16* __restrict__ wouth,
    float* __restrict__ out)
{
  __shared__ h16 As[2][8192];
  __shared__ h16 Bs[2][8192];
  const int t = threadIdx.x, lane = t & 63, w = t >> 6, g = lane >> 4, lo = lane & 15;
  const int o0 = blockIdx.x * 128;
  const int p0 = blockIdx.y * 128;
  const int b  = blockIdx.z;
  const h16* Ag = wouth + (size_t)o0 * kC;
  const h16* Bg = ah + ((size_t)b * kN + p0) * kC;

  f32x4 acc[4][4];
  #pragma unroll
  for (int mi = 0; mi < 4; mi++)
    #pragma unroll
    for (int ni = 0; ni < 4; ni++) { f32x4 z = {0.f, 0.f, 0.f, 0.f}; acc[mi][ni] = z; }

  gemm_loop_f16(Ag, Bg, As, Bs, t, w, g, lo, acc);

  const int ow = o0 + (w >> 1) * 64;
  const int pw = p0 + (w & 1) * 64;
  #pragma unroll
  for (int mi = 0; mi < 4; mi++)
    #pragma unroll
    for (int ni = 0; ni < 4; ni++) {
      const int p = pw + ni * 16 + lo;
      #pragma unroll
      for (int r = 0; r < 4; r++) {
        const int oc = ow + mi * 16 + g * 4 + r;
        out[((size_t)b * kHid + oc) * kN + p] = ((const float*)&acc[mi][ni])[r];
      }
    }
}

// ---------------------------------------------------------------------------
// Launch
// ---------------------------------------------------------------------------
extern "C" void kernel_launch(void* const* d_in, const int* in_sizes, int n_in,
                              void* d_out, int out_size, void* d_ws, size_t ws_size,
                              hipStream_t stream) {
  (void)in_sizes; (void)n_in; (void)out_size; (void)ws_size;
  const float* x      = (const float*)d_in[0];
  const float* gamma  = (const float*)d_in[1];
  const float* mem_kv = (const float*)d_in[2];
  const float* w_qkv  = (const float*)d_in[3];
  const float* w_out  = (const float*)d_in[4];
  float* out = (float*)d_out;

  h16* xh    = (h16*)d_ws;
  h16* Qh    = xh + (size_t)16777216;
  h16* Kh    = Qh + (size_t)8388608;
  h16* VTh   = Kh + (size_t)8388608;
  h16* ah    = VTh + (size_t)8388608;
  h16* wqh   = ah + (size_t)8388608;
  h16* wouth = wqh + (size_t)786432;

  rms_transpose_kernel<<<256, 256, 0, stream>>>(x, xh);
  prep_w_kernel<<<2048, 64, 0, stream>>>(w_qkv, gamma, w_out, wqh, wouth);
  qkv_mfma_kernel<<<dim3(12, 8, 16), 256, 0, stream>>>(xh, wqh, Qh, Kh, VTh);
  attn_mfma_kernel<<<1024, 256, 0, stream>>>(Qh, Kh, VTh, mem_kv, ah);
  out_mfma_kernel<<<dim3(4, 8, 16), 256, 0, stream>>>(ah, wouth, out);
}